// Round 15
// baseline (103.744 us; speedup 1.0000x reference)
//
#include <hip/hip_runtime.h>
#include <hip/hip_bf16.h>

#define NUM_AGES 100
#define FEAT 512
#define BATCH 4096
#define EPSF 1e-6f
#define INV_T 10.0f
#define INV_NORM (1.0f / ((float)BATCH * (float)(BATCH - 1)))

#define BM 128
#define BN 128
#define BK 64
// kept tiles: by <= bx, bx in [0,32) -> 32*33/2 = 528 = 8*66 (bijective XCD chunking)
#define NTILES 528

typedef __bf16 bf16_t;
typedef __bf16 v8bf __attribute__((ext_vector_type(8)));
typedef float v4f __attribute__((ext_vector_type(4)));
typedef unsigned int u32x4 __attribute__((ext_vector_type(4)));  // nt-store-legal 16B

// async global->LDS, 16B per lane; LDS dest is wave-uniform base + lane*16
__device__ __forceinline__ void async16(const void* g, void* l) {
  __builtin_amdgcn_global_load_lds(
      (const __attribute__((address_space(1))) void*)g,
      (__attribute__((address_space(3))) void*)l, 16, 0, 0);
}

// ---------------- kernel 1: prep (samples + U table) ---------------------
// v14 THEORY: pair's staging rate is pinned at ~13 GB/s/CU across ALL
// schedule variants (v5..v13: dbuf, asm vmcnt, tile 64..256, 1-4 blk/CU,
// direct-global) -> the service path itself is the constant: zb/ub/zut are
// freshly written, DIRTY in the writer-XCD's private L2 (writers round-
// robin all 8 XCDs) -> nearly every consumer read is a cross-XCD dirty-
// line snoop, and no clean L3 copy ever forms. Fix: NON-TEMPORAL stores
// (gfx950 `nt`): producer data bypasses L2 retention and lands clean in
// L3 -> consumers read at L3 rate and fill their LOCAL L2 on first touch.
// Cross-kernel visibility is guaranteed by the kernel boundary; nt only
// changes cache placement. v14b: uint4 (HIP struct) -> u32x4 ext-vector
// for builtin legality; bit-identical stores. Else byte-identical to v13.
__global__ __launch_bounds__(512) void prep_kernel(
    const float* __restrict__ z, const int* __restrict__ ages,
    const float* __restrict__ proxies,
    bf16_t* __restrict__ zb, bf16_t* __restrict__ ub,
    float* __restrict__ sq, int* __restrict__ ages_s, float* __restrict__ out)
{
  int t = threadIdx.x;
  int wv = t >> 6, lane = t & 63;

  if (blockIdx.x >= 512) {
    int a = (blockIdx.x - 512) * 8 + wv;   // 0..127
    int c0 = lane * 8;
    union { bf16_t h[8]; u32x4 u; } uw;
    if (a < NUM_AGES) {
      int an = a + 1 > NUM_AGES - 1 ? NUM_AGES - 1 : a + 1;
      int ap = a - 1 < 0 ? 0 : a - 1;
      const float4* cc4 = (const float4*)(proxies + (size_t)a  * FEAT + c0);
      const float4* cn4 = (const float4*)(proxies + (size_t)an * FEAT + c0);
      const float4* cp4 = (const float4*)(proxies + (size_t)ap * FEAT + c0);
      float df[8], db[8];
      float ff = 0.f, bb = 0.f;
#pragma unroll
      for (int h = 0; h < 2; ++h) {
        float4 c4 = cc4[h], n4 = cn4[h], p4 = cp4[h];
        float cA[4] = {c4.x, c4.y, c4.z, c4.w};
        float nA[4] = {n4.x, n4.y, n4.z, n4.w};
        float pA[4] = {p4.x, p4.y, p4.z, p4.w};
#pragma unroll
        for (int i2 = 0; i2 < 4; ++i2) {
          int i = h * 4 + i2;
          df[i] = nA[i2] - cA[i2];
          db[i] = pA[i2] - cA[i2];
          ff += df[i] * df[i];
          bb += db[i] * db[i];
        }
      }
#pragma unroll
      for (int off = 32; off > 0; off >>= 1) {
        ff += __shfl_xor(ff, off, 64);
        bb += __shfl_xor(bb, off, 64);
      }
      float rf = 1.0f / (sqrtf(ff) + EPSF);
      float rb = 1.0f / (sqrtf(bb) + EPSF);
#pragma unroll
      for (int i = 0; i < 8; ++i)
        uw.h[i] = (bf16_t)(db[i] * rb - df[i] * rf);
    } else {
      uw.u = (u32x4){0u, 0u, 0u, 0u};
    }
    int key = a & 7;
    int c2s = (c0 & ~63) | ((((c0 >> 3) & 7) ^ key) << 3);
    __builtin_nontemporal_store(uw.u, (u32x4*)((char*)ub + ((size_t)a * FEAT + c2s) * 2));
    return;
  }

  __shared__ __attribute__((aligned(16))) int sa[BATCH];   // 16 KB
  if (blockIdx.x == 0 && t == 0) out[0] = 0.0f;   // pair accumulates into out

  ((int4*)sa)[t]       = ((const int4*)ages)[t];
  ((int4*)sa)[t + 512] = ((const int4*)ages)[t + 512];
  __syncthreads();

  int j = blockIdx.x * 8 + wv;
  int araw = sa[j];

  int cnt = 0;
  const int4* sa4 = (const int4*)sa;
#pragma unroll
  for (int e = 0; e < 16; ++e) {
    int idx = lane + 64 * e;
    int4 v = sa4[idx];
    int k = idx * 4;
    cnt += (v.x < araw || (v.x == araw && k     < j)) ? 1 : 0;
    cnt += (v.y < araw || (v.y == araw && k + 1 < j)) ? 1 : 0;
    cnt += (v.z < araw || (v.z == araw && k + 2 < j)) ? 1 : 0;
    cnt += (v.w < araw || (v.w == araw && k + 3 < j)) ? 1 : 0;
  }

  int c0 = lane * 8;
  const float4* zr4 = (const float4*)(z + (size_t)j * FEAT + c0);
  float zv[8];
  float zz = 0.f;
#pragma unroll
  for (int h = 0; h < 2; ++h) {
    float4 z4 = zr4[h];
    float zA[4] = {z4.x, z4.y, z4.z, z4.w};
#pragma unroll
    for (int i2 = 0; i2 < 4; ++i2) {
      zv[h * 4 + i2] = zA[i2];
      zz += zA[i2] * zA[i2];
    }
  }
#pragma unroll
  for (int off = 32; off > 0; off >>= 1) {
    zz  += __shfl_xor(zz,  off, 64);
    cnt += __shfl_xor(cnt, off, 64);
  }
  int rank = cnt;
  int key = rank & 7;
  int c2s = (c0 & ~63) | ((((c0 >> 3) & 7) ^ key) << 3);

  union { bf16_t h[8]; u32x4 u; } uz;
#pragma unroll
  for (int i = 0; i < 8; ++i) uz.h[i] = (bf16_t)zv[i];
  __builtin_nontemporal_store(uz.u, (u32x4*)((char*)zb + ((size_t)rank * FEAT + c2s) * 2));
  if (lane == 0) {
    __builtin_nontemporal_store(zz, sq + rank);
    __builtin_nontemporal_store(araw, ages_s + rank);
  }
}

// ---------------- kernel 2: ZU = Zsorted @ U^T (32 blocks) ---------------
// v10-verified structure; v14: zut stores are non-temporal (same dirty-
// line reasoning -- pair reads up to ~32KB of zut per block in epilogue).
__global__ __launch_bounds__(256, 3) void zu_kernel(
    const bf16_t* __restrict__ zb, const bf16_t* __restrict__ ub,
    float* __restrict__ zut)
{
  __shared__ __attribute__((aligned(16))) char lds[32768];
  int t = threadIdx.x;
  int wv = t >> 6, lane = t & 63;
  int r0 = blockIdx.x * 128;

  v4f acc[4][4];
#pragma unroll
  for (int a = 0; a < 4; ++a)
#pragma unroll
    for (int b = 0; b < 4; ++b) acc[a][b] = (v4f){0.f, 0.f, 0.f, 0.f};

  int wm = wv >> 1, wn = wv & 1;
  int lm = lane & 15, q = lane >> 4;
  int psw0 = ((q    ) ^ (lm & 7)) * 16;
  int psw1 = ((q + 4) ^ (lm & 7)) * 16;
  int loff = (lane >> 3) * FEAT + (lane & 7) * 8;
  const bf16_t* baseA = zb + (size_t)r0 * FEAT + loff;
  const bf16_t* baseU = ub + loff;

  for (int k0 = 0; k0 < FEAT; k0 += BK) {
#pragma unroll
    for (int c = 0; c < 4; ++c) {
      int chunk = wv * 4 + c;
      async16(baseA + (size_t)chunk * 8 * FEAT + k0, lds + chunk * 1024);
      async16(baseU + (size_t)chunk * 8 * FEAT + k0, lds + 16384 + chunk * 1024);
    }
    __syncthreads();
#pragma unroll
    for (int s = 0; s < 2; ++s) {
      int psw = s ? psw1 : psw0;
      v8bf afr[4], bu[4];
#pragma unroll
      for (int mi = 0; mi < 4; ++mi) {
        int r = wm * 64 + mi * 16 + lm;
        afr[mi] = *(const v8bf*)(lds + r * 128 + psw);
      }
#pragma unroll
      for (int ni = 0; ni < 4; ++ni) {
        int r = wn * 64 + ni * 16 + lm;
        bu[ni] = *(const v8bf*)(lds + 16384 + r * 128 + psw);
      }
#pragma unroll
      for (int mi = 0; mi < 4; ++mi)
#pragma unroll
        for (int ni = 0; ni < 4; ++ni)
          acc[mi][ni] = __builtin_amdgcn_mfma_f32_16x16x32_bf16(afr[mi], bu[ni], acc[mi][ni], 0, 0, 0);
    }
    __syncthreads();
  }

#pragma unroll
  for (int ni = 0; ni < 4; ++ni) {
    int age = wn * 64 + ni * 16 + lm;
#pragma unroll
    for (int mi = 0; mi < 4; ++mi) {
      int rb0 = r0 + wm * 64 + mi * 16 + q * 4;
      __builtin_nontemporal_store(acc[mi][ni], (v4f*)(zut + (size_t)age * BATCH + rb0));
    }
  }
}

// ---------------- kernel 3: pairwise G-GEMM (v13 structure, unchanged) ---
// 528-tile 128^2 XCD-chunked triangle, 4 waves of 64x64, single-buffered
// stage->sync->compute->sync, (256,4) = 4 blocks/CU. Byte-identical to
// v13's pair: v14 changes only the PRODUCERS' cache policy.
__global__ __launch_bounds__(256, 4) void pair_kernel(
    const bf16_t* __restrict__ zb, const float* __restrict__ zut,
    const float* __restrict__ sq, const int* __restrict__ ages,
    float* __restrict__ out)
{
  // A: 128x64 bf16 = 16384 B | Z: 128x64 bf16 = 16384 B
  __shared__ __attribute__((aligned(16))) char lds[32768];
  __shared__ float s_sqi[BM];
  __shared__ int   s_agei[BM];
  __shared__ float s_sqj[BN];
  __shared__ float s_hdj[BN];
  __shared__ int   s_agej[BN];
  __shared__ float wsum[4];

  int t = threadIdx.x;
  int wv = t >> 6, lane = t & 63;

  // ---- tile decode: XCD chunk + column-major triangle (by <= bx) ----
  int id = (blockIdx.x & 7) * (NTILES / 8) + (blockIdx.x >> 3);
  int bx = 0, rem = id;
  while (rem >= bx + 1) { rem -= bx + 1; ++bx; }
  int by = rem;
  int i0 = by * BM, j0 = bx * BN;

  if (t < BM) {
    s_sqi[t] = sq[i0 + t];
    s_agei[t] = ages[i0 + t];
  } else {
    int u = t - BM;
    int raw = ages[j0 + u];
    int ac = raw < 0 ? 0 : (raw > NUM_AGES - 1 ? NUM_AGES - 1 : raw);
    s_sqj[u] = sq[j0 + u];
    s_agej[u] = raw;
    s_hdj[u] = zut[(size_t)ac * BATCH + j0 + u];
  }

  v4f accG[4][4];
#pragma unroll
  for (int a = 0; a < 4; ++a)
#pragma unroll
    for (int b = 0; b < 4; ++b) accG[a][b] = (v4f){0.f, 0.f, 0.f, 0.f};

  int wm = wv >> 1, wn = wv & 1;        // wave grid 2x2: 64 rows x 64 cols
  int lm = lane & 15, q = lane >> 4;
  int psw0 = ((q    ) ^ (lm & 7)) * 16;
  int psw1 = ((q + 4) ^ (lm & 7)) * 16;

  int loff = (lane >> 3) * FEAT + (lane & 7) * 8;
  const bf16_t* baseA = zb + (size_t)i0 * FEAT + loff;
  const bf16_t* baseZ = zb + (size_t)j0 * FEAT + loff;

  for (int k0 = 0; k0 < FEAT; k0 += BK) {
#pragma unroll
    for (int c = 0; c < 4; ++c) {
      int chunk = wv * 4 + c;
      async16(baseA + (size_t)chunk * 8 * FEAT + k0, lds + chunk * 1024);
      async16(baseZ + (size_t)chunk * 8 * FEAT + k0, lds + 16384 + chunk * 1024);
    }
    __syncthreads();   // implicit vmcnt(0): tile staged

#pragma unroll
    for (int s = 0; s < 2; ++s) {
      int psw = s ? psw1 : psw0;
      v8bf afr[4], bz[4];
#pragma unroll
      for (int mi = 0; mi < 4; ++mi) {
        int r = wm * 64 + mi * 16 + lm;
        afr[mi] = *(const v8bf*)(lds + r * 128 + psw);
      }
#pragma unroll
      for (int ni = 0; ni < 4; ++ni) {
        int r = wn * 64 + ni * 16 + lm;
        bz[ni] = *(const v8bf*)(lds + 16384 + r * 128 + psw);
      }
#pragma unroll
      for (int mi = 0; mi < 4; ++mi)
#pragma unroll
        for (int ni = 0; ni < 4; ++ni)
          accG[mi][ni] = __builtin_amdgcn_mfma_f32_16x16x32_bf16(afr[mi], bz[ni], accG[mi][ni], 0, 0, 0);
    }
    __syncthreads();   // WAR before next staging
  }

  // epilogue: C/D col = lane&15 (-> j), row = q*4+reg (-> i);
  // h = ZUT[a_j][i] gathered float4 (i consecutive over reg)
  float tsum = 0.f;
#pragma unroll
  for (int ni = 0; ni < 4; ++ni) {
    int jl = wn * 64 + ni * 16 + lm;
    float sqj = s_sqj[jl];
    float hdj = s_hdj[jl];
    int aj = s_agej[jl];
    int ac = aj < 0 ? 0 : (aj > NUM_AGES - 1 ? NUM_AGES - 1 : aj);
    const float* zrow = zut + (size_t)ac * BATCH + i0;
#pragma unroll
    for (int mi = 0; mi < 4; ++mi) {
      int ilb = wm * 64 + mi * 16 + q * 4;
      float4 h4 = *(const float4*)(zrow + ilb);
      float hh[4] = {h4.x, h4.y, h4.z, h4.w};
#pragma unroll
      for (int r = 0; r < 4; ++r) {
        int il = ilb + r;
        float g = accG[mi][ni][r];
        float d2 = fmaxf(s_sqi[il] + sqj - 2.0f * g, 1e-12f);
        float rs = __builtin_amdgcn_rsqf(d2);
        float arg = (hh[r] - hdj) * INV_T * rs;
        float sp = fmaxf(arg, 0.0f) + __logf(1.0f + __expf(-fabsf(arg)));
        tsum += (s_agei[il] < aj) ? sp : 0.0f;
      }
    }
  }

#pragma unroll
  for (int off = 32; off > 0; off >>= 1) tsum += __shfl_down(tsum, off, 64);
  if (lane == 0) wsum[wv] = tsum;
  __syncthreads();
  if (t == 0)
    atomicAdd(out, (wsum[0] + wsum[1] + wsum[2] + wsum[3]) * INV_NORM);
}

extern "C" void kernel_launch(void* const* d_in, const int* in_sizes, int n_in,
                              void* d_out, int out_size, void* d_ws, size_t ws_size,
                              hipStream_t stream) {
  const float* z = (const float*)d_in[0];
  const int* ages = (const int*)d_in[1];
  const float* proxies = (const float*)d_in[2];
  float* out = (float*)d_out;

  char* ws = (char*)d_ws;
  bf16_t* zb  = (bf16_t*)ws;                                  // 4 MB
  bf16_t* ub  = (bf16_t*)(ws + (size_t)4 * 1024 * 1024);      // 128 KB
  float*  zut = (float*) (ws + (size_t)6 * 1024 * 1024);      // 2 MB (128x4096 f32)
  float*  sq     = (float*)(ws + (size_t)8 * 1024 * 1024);    // 16 KB
  int*    ages_s = (int*)  (ws + (size_t)8 * 1024 * 1024 + 16384);

  prep_kernel<<<528, 512, 0, stream>>>(z, ages, proxies, zb, ub, sq, ages_s, out);
  zu_kernel<<<32, 256, 0, stream>>>(zb, ub, zut);
  pair_kernel<<<NTILES, 256, 0, stream>>>(zb, zut, sq, ages_s, out);
}

// Round 16
// 96.906 us; speedup vs baseline: 1.0706x; 1.0706x over previous
//
#include <hip/hip_runtime.h>
#include <hip/hip_bf16.h>

#define NUM_AGES 100
#define FEAT 512
#define BATCH 4096
#define EPSF 1e-6f
#define INV_T 10.0f
#define INV_NORM (1.0f / ((float)BATCH * (float)(BATCH - 1)))

#define BM 128
#define BN 128
#define BK 64
// kept tiles: by <= bx, bx in [0,32) -> 32*33/2 = 528 = 8*66 (bijective XCD chunking)
#define NTILES 528

typedef __bf16 bf16_t;
typedef __bf16 v8bf __attribute__((ext_vector_type(8)));
typedef float v4f __attribute__((ext_vector_type(4)));

// async global->LDS, 16B per lane; LDS dest is wave-uniform base + lane*16
__device__ __forceinline__ void async16(const void* g, void* l) {
  __builtin_amdgcn_global_load_lds(
      (const __attribute__((address_space(1))) void*)g,
      (__attribute__((address_space(3))) void*)l, 16, 0, 0);
}

// ---------------- kernel 1: prep (samples + U table) — v10, best-measured -
// Factorization: w_j depends only on age a_j (100 distinct w vectors);
// H[i,j] = ZU[i, a_j], ZU = Z @ U^T. Blocks 0..511: one wave per sample
// (rank scan via LDS int4, butterfly reduce, pre-swizzled bf16 z store).
// Blocks 512..527: U-table rows (128 padded, pre-swizzled by a&7).
// SESSION FINAL: this is the exact v10 source (96.7us total, best of 9
// passing rounds). Levers tested-and-neutral on pair (~40us): schedule
// depth, tile 64^2-256^2, 1-4 blocks/CU, staged bytes 270->70MB, LDS-vs-
// direct-global, nt producer stores. Real wins: W-factorization (this),
// wave-per-sample prep, XCD-chunked triangle, pre-swizzle, spill-safe
// launch bounds. Remaining time: ~44us harness fill (HBM-bound,
// uncontrollable) + per-CU staging-service floor in pair.
__global__ __launch_bounds__(512) void prep_kernel(
    const float* __restrict__ z, const int* __restrict__ ages,
    const float* __restrict__ proxies,
    bf16_t* __restrict__ zb, bf16_t* __restrict__ ub,
    float* __restrict__ sq, int* __restrict__ ages_s, float* __restrict__ out)
{
  int t = threadIdx.x;
  int wv = t >> 6, lane = t & 63;

  if (blockIdx.x >= 512) {
    int a = (blockIdx.x - 512) * 8 + wv;   // 0..127
    int c0 = lane * 8;
    union { bf16_t h[8]; uint4 u; } uw;
    if (a < NUM_AGES) {
      int an = a + 1 > NUM_AGES - 1 ? NUM_AGES - 1 : a + 1;
      int ap = a - 1 < 0 ? 0 : a - 1;
      const float4* cc4 = (const float4*)(proxies + (size_t)a  * FEAT + c0);
      const float4* cn4 = (const float4*)(proxies + (size_t)an * FEAT + c0);
      const float4* cp4 = (const float4*)(proxies + (size_t)ap * FEAT + c0);
      float df[8], db[8];
      float ff = 0.f, bb = 0.f;
#pragma unroll
      for (int h = 0; h < 2; ++h) {
        float4 c4 = cc4[h], n4 = cn4[h], p4 = cp4[h];
        float cA[4] = {c4.x, c4.y, c4.z, c4.w};
        float nA[4] = {n4.x, n4.y, n4.z, n4.w};
        float pA[4] = {p4.x, p4.y, p4.z, p4.w};
#pragma unroll
        for (int i2 = 0; i2 < 4; ++i2) {
          int i = h * 4 + i2;
          df[i] = nA[i2] - cA[i2];
          db[i] = pA[i2] - cA[i2];
          ff += df[i] * df[i];
          bb += db[i] * db[i];
        }
      }
#pragma unroll
      for (int off = 32; off > 0; off >>= 1) {
        ff += __shfl_xor(ff, off, 64);
        bb += __shfl_xor(bb, off, 64);
      }
      float rf = 1.0f / (sqrtf(ff) + EPSF);
      float rb = 1.0f / (sqrtf(bb) + EPSF);
#pragma unroll
      for (int i = 0; i < 8; ++i)
        uw.h[i] = (bf16_t)(db[i] * rb - df[i] * rf);
    } else {
      uw.u = (uint4){0u, 0u, 0u, 0u};
    }
    int key = a & 7;
    int c2s = (c0 & ~63) | ((((c0 >> 3) & 7) ^ key) << 3);
    *(uint4*)((char*)ub + ((size_t)a * FEAT + c2s) * 2) = uw.u;
    return;
  }

  __shared__ __attribute__((aligned(16))) int sa[BATCH];   // 16 KB
  if (blockIdx.x == 0 && t == 0) out[0] = 0.0f;   // pair accumulates into out

  ((int4*)sa)[t]       = ((const int4*)ages)[t];
  ((int4*)sa)[t + 512] = ((const int4*)ages)[t + 512];
  __syncthreads();

  int j = blockIdx.x * 8 + wv;
  int araw = sa[j];

  int cnt = 0;
  const int4* sa4 = (const int4*)sa;
#pragma unroll
  for (int e = 0; e < 16; ++e) {
    int idx = lane + 64 * e;
    int4 v = sa4[idx];
    int k = idx * 4;
    cnt += (v.x < araw || (v.x == araw && k     < j)) ? 1 : 0;
    cnt += (v.y < araw || (v.y == araw && k + 1 < j)) ? 1 : 0;
    cnt += (v.z < araw || (v.z == araw && k + 2 < j)) ? 1 : 0;
    cnt += (v.w < araw || (v.w == araw && k + 3 < j)) ? 1 : 0;
  }

  int c0 = lane * 8;
  const float4* zr4 = (const float4*)(z + (size_t)j * FEAT + c0);
  float zv[8];
  float zz = 0.f;
#pragma unroll
  for (int h = 0; h < 2; ++h) {
    float4 z4 = zr4[h];
    float zA[4] = {z4.x, z4.y, z4.z, z4.w};
#pragma unroll
    for (int i2 = 0; i2 < 4; ++i2) {
      zv[h * 4 + i2] = zA[i2];
      zz += zA[i2] * zA[i2];
    }
  }
#pragma unroll
  for (int off = 32; off > 0; off >>= 1) {
    zz  += __shfl_xor(zz,  off, 64);
    cnt += __shfl_xor(cnt, off, 64);
  }
  int rank = cnt;
  int key = rank & 7;
  int c2s = (c0 & ~63) | ((((c0 >> 3) & 7) ^ key) << 3);

  union { bf16_t h[8]; uint4 u; } uz;
#pragma unroll
  for (int i = 0; i < 8; ++i) uz.h[i] = (bf16_t)zv[i];
  *(uint4*)((char*)zb + ((size_t)rank * FEAT + c2s) * 2) = uz.u;
  if (lane == 0) {
    sq[rank] = zz;
    ages_s[rank] = araw;
  }
}

// ---------------- kernel 2: ZU = Zsorted @ U^T (32 blocks) — v10 ---------
// Verified 4-wave 64x64 MFMA structure. Output ZUT[age][rank] f32
// (transposed for pair's row-gathers), rows 100..127 zeros (never read).
__global__ __launch_bounds__(256, 3) void zu_kernel(
    const bf16_t* __restrict__ zb, const bf16_t* __restrict__ ub,
    float* __restrict__ zut)
{
  __shared__ __attribute__((aligned(16))) char lds[32768];
  int t = threadIdx.x;
  int wv = t >> 6, lane = t & 63;
  int r0 = blockIdx.x * 128;

  v4f acc[4][4];
#pragma unroll
  for (int a = 0; a < 4; ++a)
#pragma unroll
    for (int b = 0; b < 4; ++b) acc[a][b] = (v4f){0.f, 0.f, 0.f, 0.f};

  int wm = wv >> 1, wn = wv & 1;
  int lm = lane & 15, q = lane >> 4;
  int psw0 = ((q    ) ^ (lm & 7)) * 16;
  int psw1 = ((q + 4) ^ (lm & 7)) * 16;
  int loff = (lane >> 3) * FEAT + (lane & 7) * 8;
  const bf16_t* baseA = zb + (size_t)r0 * FEAT + loff;
  const bf16_t* baseU = ub + loff;

  for (int k0 = 0; k0 < FEAT; k0 += BK) {
#pragma unroll
    for (int c = 0; c < 4; ++c) {
      int chunk = wv * 4 + c;
      async16(baseA + (size_t)chunk * 8 * FEAT + k0, lds + chunk * 1024);
      async16(baseU + (size_t)chunk * 8 * FEAT + k0, lds + 16384 + chunk * 1024);
    }
    __syncthreads();
#pragma unroll
    for (int s = 0; s < 2; ++s) {
      int psw = s ? psw1 : psw0;
      v8bf afr[4], bu[4];
#pragma unroll
      for (int mi = 0; mi < 4; ++mi) {
        int r = wm * 64 + mi * 16 + lm;
        afr[mi] = *(const v8bf*)(lds + r * 128 + psw);
      }
#pragma unroll
      for (int ni = 0; ni < 4; ++ni) {
        int r = wn * 64 + ni * 16 + lm;
        bu[ni] = *(const v8bf*)(lds + 16384 + r * 128 + psw);
      }
#pragma unroll
      for (int mi = 0; mi < 4; ++mi)
#pragma unroll
        for (int ni = 0; ni < 4; ++ni)
          acc[mi][ni] = __builtin_amdgcn_mfma_f32_16x16x32_bf16(afr[mi], bu[ni], acc[mi][ni], 0, 0, 0);
    }
    __syncthreads();
  }

  // C/D layout: col = lane&15 -> age (B side), row = q*4+reg -> rank (A side)
#pragma unroll
  for (int ni = 0; ni < 4; ++ni) {
    int age = wn * 64 + ni * 16 + lm;
#pragma unroll
    for (int mi = 0; mi < 4; ++mi) {
      int rb0 = r0 + wm * 64 + mi * 16 + q * 4;
      *(v4f*)(zut + (size_t)age * BATCH + rb0) = acc[mi][ni];
    }
  }
}

// ---------------- kernel 3: pairwise G-GEMM (v10, best-measured) ---------
// 528-tile 128^2 XCD-chunked column-major triangle, 4 waves of 64x64,
// single-buffered stage->sync->compute->sync, (256,3) = 3 blocks/CU.
// Epilogue: h = ZUT[a_j][i] gathered as float4 (rank-consecutive, 16B
// aligned); hdj = ZUT[a_j][j] staged per block. No spill (170-reg cap
// >= ~134 needed; v4's (512,6) spill lesson).
__global__ __launch_bounds__(256, 3) void pair_kernel(
    const bf16_t* __restrict__ zb, const float* __restrict__ zut,
    const float* __restrict__ sq, const int* __restrict__ ages,
    float* __restrict__ out)
{
  // A: 128x64 bf16 = 16384 B | Z: 128x64 bf16 = 16384 B
  __shared__ __attribute__((aligned(16))) char lds[32768];
  __shared__ float s_sqi[BM];
  __shared__ int   s_agei[BM];
  __shared__ float s_sqj[BN];
  __shared__ float s_hdj[BN];
  __shared__ int   s_agej[BN];
  __shared__ float wsum[4];

  int t = threadIdx.x;
  int wv = t >> 6, lane = t & 63;

  // ---- tile decode: XCD chunk + column-major triangle (by <= bx) ----
  int id = (blockIdx.x & 7) * (NTILES / 8) + (blockIdx.x >> 3);
  int bx = 0, rem = id;
  while (rem >= bx + 1) { rem -= bx + 1; ++bx; }
  int by = rem;
  int i0 = by * BM, j0 = bx * BN;

  if (t < BM) {
    s_sqi[t] = sq[i0 + t];
    s_agei[t] = ages[i0 + t];
  } else {
    int u = t - BM;
    int raw = ages[j0 + u];
    int ac = raw < 0 ? 0 : (raw > NUM_AGES - 1 ? NUM_AGES - 1 : raw);
    s_sqj[u] = sq[j0 + u];
    s_agej[u] = raw;
    s_hdj[u] = zut[(size_t)ac * BATCH + j0 + u];
  }

  v4f accG[4][4];
#pragma unroll
  for (int a = 0; a < 4; ++a)
#pragma unroll
    for (int b = 0; b < 4; ++b) accG[a][b] = (v4f){0.f, 0.f, 0.f, 0.f};

  int wm = wv >> 1, wn = wv & 1;        // wave grid 2x2: 64 rows x 64 cols
  int lm = lane & 15, q = lane >> 4;
  int psw0 = ((q    ) ^ (lm & 7)) * 16;
  int psw1 = ((q + 4) ^ (lm & 7)) * 16;

  int loff = (lane >> 3) * FEAT + (lane & 7) * 8;
  const bf16_t* baseA = zb + (size_t)i0 * FEAT + loff;
  const bf16_t* baseZ = zb + (size_t)j0 * FEAT + loff;

  for (int k0 = 0; k0 < FEAT; k0 += BK) {
#pragma unroll
    for (int c = 0; c < 4; ++c) {
      int chunk = wv * 4 + c;
      async16(baseA + (size_t)chunk * 8 * FEAT + k0, lds + chunk * 1024);
      async16(baseZ + (size_t)chunk * 8 * FEAT + k0, lds + 16384 + chunk * 1024);
    }
    __syncthreads();   // implicit vmcnt(0): tile staged

#pragma unroll
    for (int s = 0; s < 2; ++s) {
      int psw = s ? psw1 : psw0;
      v8bf afr[4], bz[4];
#pragma unroll
      for (int mi = 0; mi < 4; ++mi) {
        int r = wm * 64 + mi * 16 + lm;
        afr[mi] = *(const v8bf*)(lds + r * 128 + psw);
      }
#pragma unroll
      for (int ni = 0; ni < 4; ++ni) {
        int r = wn * 64 + ni * 16 + lm;
        bz[ni] = *(const v8bf*)(lds + 16384 + r * 128 + psw);
      }
#pragma unroll
      for (int mi = 0; mi < 4; ++mi)
#pragma unroll
        for (int ni = 0; ni < 4; ++ni)
          accG[mi][ni] = __builtin_amdgcn_mfma_f32_16x16x32_bf16(afr[mi], bz[ni], accG[mi][ni], 0, 0, 0);
    }
    __syncthreads();   // WAR before next staging
  }

  // epilogue: C/D col = lane&15 (-> j), row = q*4+reg (-> i);
  // h = ZUT[a_j][i] gathered float4 (i consecutive over reg)
  float tsum = 0.f;
#pragma unroll
  for (int ni = 0; ni < 4; ++ni) {
    int jl = wn * 64 + ni * 16 + lm;
    float sqj = s_sqj[jl];
    float hdj = s_hdj[jl];
    int aj = s_agej[jl];
    int ac = aj < 0 ? 0 : (aj > NUM_AGES - 1 ? NUM_AGES - 1 : aj);
    const float* zrow = zut + (size_t)ac * BATCH + i0;
#pragma unroll
    for (int mi = 0; mi < 4; ++mi) {
      int ilb = wm * 64 + mi * 16 + q * 4;
      float4 h4 = *(const float4*)(zrow + ilb);
      float hh[4] = {h4.x, h4.y, h4.z, h4.w};
#pragma unroll
      for (int r = 0; r < 4; ++r) {
        int il = ilb + r;
        float g = accG[mi][ni][r];
        float d2 = fmaxf(s_sqi[il] + sqj - 2.0f * g, 1e-12f);
        float rs = __builtin_amdgcn_rsqf(d2);
        float arg = (hh[r] - hdj) * INV_T * rs;
        float sp = fmaxf(arg, 0.0f) + __logf(1.0f + __expf(-fabsf(arg)));
        tsum += (s_agei[il] < aj) ? sp : 0.0f;
      }
    }
  }

#pragma unroll
  for (int off = 32; off > 0; off >>= 1) tsum += __shfl_down(tsum, off, 64);
  if (lane == 0) wsum[wv] = tsum;
  __syncthreads();
  if (t == 0)
    atomicAdd(out, (wsum[0] + wsum[1] + wsum[2] + wsum[3]) * INV_NORM);
}

extern "C" void kernel_launch(void* const* d_in, const int* in_sizes, int n_in,
                              void* d_out, int out_size, void* d_ws, size_t ws_size,
                              hipStream_t stream) {
  const float* z = (const float*)d_in[0];
  const int* ages = (const int*)d_in[1];
  const float* proxies = (const float*)d_in[2];
  float* out = (float*)d_out;

  char* ws = (char*)d_ws;
  bf16_t* zb  = (bf16_t*)ws;                                  // 4 MB
  bf16_t* ub  = (bf16_t*)(ws + (size_t)4 * 1024 * 1024);      // 128 KB
  float*  zut = (float*) (ws + (size_t)6 * 1024 * 1024);      // 2 MB (128x4096 f32)
  float*  sq     = (float*)(ws + (size_t)8 * 1024 * 1024);    // 16 KB
  int*    ages_s = (int*)  (ws + (size_t)8 * 1024 * 1024 + 16384);

  prep_kernel<<<528, 512, 0, stream>>>(z, ages, proxies, zb, ub, sq, ages_s, out);
  zu_kernel<<<32, 256, 0, stream>>>(zb, ub, zut);
  pair_kernel<<<NTILES, 256, 0, stream>>>(zb, zut, sq, ages_s, out);
}